// Round 1
// baseline (1135.979 us; speedup 1.0000x reference)
//
#include <hip/hip_runtime.h>
#include <hip/hip_bf16.h>

typedef __bf16 bf16_t;
typedef __bf16 bf16x8 __attribute__((ext_vector_type(8)));
typedef __bf16 bf16x4 __attribute__((ext_vector_type(4)));
typedef float  f32x4  __attribute__((ext_vector_type(4)));

#define B_    2
#define S_    2048
#define HID_  2048
#define H_    16
#define DH_   192
#define DR_   64
#define DN_   128
#define QL_   512
#define NROWS (B_*S_)          // 4096
#define QKD   (H_*DH_)         // 3072

// ---------------- cast f32 -> bf16 (vec4) ----------------
__global__ void cast_f32_to_bf16(const float* __restrict__ in, bf16_t* __restrict__ out, int n4) {
  int i = blockIdx.x * blockDim.x + threadIdx.x;
  if (i >= n4) return;
  const float4 v = reinterpret_cast<const float4*>(in)[i];
  bf16x4 r;
  r[0] = (bf16_t)v.x; r[1] = (bf16_t)v.y; r[2] = (bf16_t)v.z; r[3] = (bf16_t)v.w;
  reinterpret_cast<bf16x4*>(out)[i] = r;
}

// ---------------- generic bf16 MFMA GEMM ----------------
// C[M,N] = A[M,K] * B[K,N];  OMODE 0: f32 C, 1: bf16 C, 2: bf16 C^T (N x M)
#define BM 64
#define BN 64
#define BK 64
#define LDT 72   // padded LDS stride (bf16 elems); 72*2=144 bytes (16B aligned, bank-spread)

template<int OMODE>
__global__ __launch_bounds__(256) void gemm_kernel(
    const bf16_t* __restrict__ A, const bf16_t* __restrict__ B,
    void* __restrict__ C, int M, int N, int K) {
  __shared__ bf16_t sA[BM][LDT];
  __shared__ bf16_t sB[BN][LDT];   // transposed tile: [n][k]
  const int tid = threadIdx.x;
  const int w  = tid >> 6;
  const int l  = tid & 63;
  const int lg = l >> 4, lr = l & 15;
  const int m0 = blockIdx.y * BM, n0 = blockIdx.x * BN;

  f32x4 acc[4];
#pragma unroll
  for (int c = 0; c < 4; ++c) acc[c] = f32x4{0.f, 0.f, 0.f, 0.f};

  for (int k0 = 0; k0 < K; k0 += BK) {
#pragma unroll
    for (int i = 0; i < 2; ++i) {
      int cid = tid + i * 256;          // 0..511
      int row = cid >> 3;               // 0..63
      int cb  = (cid & 7) * 8;          // 0..56
      uint4 va = *reinterpret_cast<const uint4*>(&A[(size_t)(m0 + row) * K + k0 + cb]);
      *reinterpret_cast<uint4*>(&sA[row][cb]) = va;
      uint4 vb = *reinterpret_cast<const uint4*>(&B[(size_t)(k0 + row) * N + n0 + cb]);
      const bf16_t* pb = reinterpret_cast<const bf16_t*>(&vb);
#pragma unroll
      for (int e = 0; e < 8; ++e) sB[cb + e][row] = pb[e];
    }
    __syncthreads();
#pragma unroll
    for (int ks = 0; ks < 2; ++ks) {
      bf16x8 af = *reinterpret_cast<const bf16x8*>(&sA[w * 16 + lr][ks * 32 + lg * 8]);
#pragma unroll
      for (int c = 0; c < 4; ++c) {
        bf16x8 bfr = *reinterpret_cast<const bf16x8*>(&sB[c * 16 + lr][ks * 32 + lg * 8]);
        acc[c] = __builtin_amdgcn_mfma_f32_16x16x32_bf16(af, bfr, acc[c], 0, 0, 0);
      }
    }
    __syncthreads();
  }
#pragma unroll
  for (int c = 0; c < 4; ++c) {
#pragma unroll
    for (int r = 0; r < 4; ++r) {
      int row = m0 + w * 16 + lg * 4 + r;
      int col = n0 + c * 16 + lr;
      float v = acc[c][r];
      if (OMODE == 0)      ((float*)C)[(size_t)row * N + col]  = v;
      else if (OMODE == 1) ((bf16_t*)C)[(size_t)row * N + col] = (bf16_t)v;
      else                 ((bf16_t*)C)[(size_t)col * M + row] = (bf16_t)v;  // C^T
    }
  }
}

// ---------------- RMSNorm (in-place, one wave per row of 512) ----------------
__global__ __launch_bounds__(64) void rmsnorm_kernel(bf16_t* __restrict__ qa,
                                                     const float* __restrict__ wnorm) {
  int row = blockIdx.x;
  int l = threadIdx.x;
  bf16x8 v = *reinterpret_cast<const bf16x8*>(&qa[(size_t)row * QL_ + l * 8]);
  float f[8];
  float ss = 0.f;
#pragma unroll
  for (int e = 0; e < 8; ++e) { f[e] = (float)v[e]; ss += f[e] * f[e]; }
#pragma unroll
  for (int off = 32; off >= 1; off >>= 1) ss += __shfl_xor(ss, off);
  float rstd = rsqrtf(ss * (1.0f / 512.0f) + 1e-6f);
  bf16x8 o;
#pragma unroll
  for (int e = 0; e < 8; ++e) o[e] = (bf16_t)(f[e] * rstd * wnorm[l * 8 + e]);
  *reinterpret_cast<bf16x8*>(&qa[(size_t)row * QL_ + l * 8]) = o;
}

// ---------------- RoPE ----------------
// q: (NROWS, 3072); rope on dims [h*192+128, h*192+192) pairs (d, d+32)
__global__ void rope_q_kernel(bf16_t* __restrict__ q) {
  int idx = blockIdx.x * blockDim.x + threadIdx.x;  // NROWS*16*32
  int d   = idx & 31;
  int h   = (idx >> 5) & 15;
  int row = idx >> 9;
  if (row >= NROWS) return;
  int s = row & (S_ - 1);
  float freq = (float)s * expf(-(float)d * (9.210340371976184f / 32.0f));  // s * 10000^(-d/32)
  float sn, cs;
  sincosf(freq, &sn, &cs);
  size_t base = (size_t)row * QKD + h * DH_ + DN_ + d;
  float q1 = (float)q[base], q2 = (float)q[base + 32];
  q[base]      = (bf16_t)(q1 * cs - q2 * sn);
  q[base + 32] = (bf16_t)(q2 * cs + q1 * sn);
}

__global__ void rope_k_kernel(bf16_t* __restrict__ k) {
  int idx = blockIdx.x * blockDim.x + threadIdx.x;  // NROWS*32
  int d   = idx & 31;
  int row = idx >> 5;
  if (row >= NROWS) return;
  int s = row & (S_ - 1);
  float freq = (float)s * expf(-(float)d * (9.210340371976184f / 32.0f));
  float sn, cs;
  sincosf(freq, &sn, &cs);
  size_t base = (size_t)row * DH_ + DN_ + d;
  float k1 = (float)k[base], k2 = (float)k[base + 32];
  k[base]      = (bf16_t)(k1 * cs - k2 * sn);
  k[base + 32] = (bf16_t)(k2 * cs + k1 * sn);
}

// ---------------- causal flash attention with sink ----------------
#define QB 64
#define KB 64
#define SK_LDT 200   // (192+8)
#define SV_LDT 72    // (64+8)
#define SP_LDT 72

__global__ __launch_bounds__(256) void attn_kernel(
    const bf16_t* __restrict__ q, const bf16_t* __restrict__ k,
    const bf16_t* __restrict__ vt, const float* __restrict__ sink,
    bf16_t* __restrict__ attn) {
  __shared__ bf16_t sK[KB][SK_LDT];     // [key][feat]
  __shared__ bf16_t sV[DH_][SV_LDT];    // V^T tile: [feat][key]
  __shared__ bf16_t sP[4][16][SP_LDT];  // per-wave P: [qrow][key]
  const int tid = threadIdx.x;
  const int w  = tid >> 6;
  const int l  = tid & 63;
  const int lg = l >> 4, lr = l & 15;
  const int qt = blockIdx.x;
  const int bh = blockIdx.y;
  const int b  = bh >> 4, h = bh & 15;

  // Q fragments held in registers for the whole block (Q-hoist)
  bf16x8 qf[6];
  {
    size_t rowoff = (size_t)(b * S_ + qt * QB + w * 16 + lr) * QKD + h * DH_;
#pragma unroll
    for (int ks = 0; ks < 6; ++ks)
      qf[ks] = *reinterpret_cast<const bf16x8*>(&q[rowoff + ks * 32 + lg * 8]);
  }

  f32x4 acc[12];
#pragma unroll
  for (int c = 0; c < 12; ++c) acc[c] = f32x4{0.f, 0.f, 0.f, 0.f};
  float m[4], lden[4];
  float sk = sink[h];
#pragma unroll
  for (int r = 0; r < 4; ++r) { m[r] = sk; lden[r] = 1.0f; }  // sink: m0=sink, l0=exp(sink-m0)=1

  const float scale = 0.07216878364870323f;  // 192^-0.5

  for (int kt = 0; kt <= qt; ++kt) {
    // stage K tile and V^T tile
#pragma unroll
    for (int i = 0; i < 6; ++i) {
      int cid = tid + i * 256;                     // 0..1535
      int krow = cid / 24, kcb = (cid % 24) * 8;   // 24 chunks per key row (192 feats)
      uint4 vk = *reinterpret_cast<const uint4*>(
          &k[(size_t)(b * S_ + kt * KB + krow) * DH_ + kcb]);
      *reinterpret_cast<uint4*>(&sK[krow][kcb]) = vk;
      int f = cid >> 3, vcb = (cid & 7) * 8;       // 8 chunks per feature row (64 keys)
      uint4 vv = *reinterpret_cast<const uint4*>(
          &vt[(size_t)f * NROWS + b * S_ + kt * KB + vcb]);
      *reinterpret_cast<uint4*>(&sV[f][vcb]) = vv;
    }
    __syncthreads();

    // QK^T
    f32x4 sc[4];
#pragma unroll
    for (int c = 0; c < 4; ++c) sc[c] = f32x4{0.f, 0.f, 0.f, 0.f};
#pragma unroll
    for (int c = 0; c < 4; ++c) {
#pragma unroll
      for (int ks = 0; ks < 6; ++ks) {
        bf16x8 kf = *reinterpret_cast<const bf16x8*>(&sK[c * 16 + lr][ks * 32 + lg * 8]);
        sc[c] = __builtin_amdgcn_mfma_f32_16x16x32_bf16(qf[ks], kf, sc[c], 0, 0, 0);
      }
    }

    // scale + causal mask
    float pv[4][4];
#pragma unroll
    for (int c = 0; c < 4; ++c) {
      int j = kt * KB + c * 16 + lr;
#pragma unroll
      for (int r = 0; r < 4; ++r) {
        float s = sc[c][r] * scale;
        int i = qt * QB + w * 16 + lg * 4 + r;
        if (kt == qt && j > i) s = -1e30f;
        pv[c][r] = s;
      }
    }
    // online softmax update (rows live across 16 lanes of the lane-group)
    float rmax[4], alpha[4], psum[4];
#pragma unroll
    for (int r = 0; r < 4; ++r) {
      rmax[r] = fmaxf(fmaxf(pv[0][r], pv[1][r]), fmaxf(pv[2][r], pv[3][r]));
    }
#pragma unroll
    for (int off = 1; off < 16; off <<= 1) {
#pragma unroll
      for (int r = 0; r < 4; ++r) rmax[r] = fmaxf(rmax[r], __shfl_xor(rmax[r], off));
    }
#pragma unroll
    for (int r = 0; r < 4; ++r) {
      float mn = fmaxf(m[r], rmax[r]);
      alpha[r] = expf(m[r] - mn);
      m[r] = mn;
      psum[r] = 0.f;
    }
#pragma unroll
    for (int c = 0; c < 4; ++c) {
#pragma unroll
      for (int r = 0; r < 4; ++r) {
        float p = expf(pv[c][r] - m[r]);
        pv[c][r] = p;
        psum[r] += p;
      }
    }
#pragma unroll
    for (int off = 1; off < 16; off <<= 1) {
#pragma unroll
      for (int r = 0; r < 4; ++r) psum[r] += __shfl_xor(psum[r], off);
    }
#pragma unroll
    for (int r = 0; r < 4; ++r) lden[r] = lden[r] * alpha[r] + psum[r];
    // rescale accumulator
#pragma unroll
    for (int c = 0; c < 12; ++c) {
#pragma unroll
      for (int r = 0; r < 4; ++r) acc[c][r] *= alpha[r];
    }
    // write P (bf16) to per-wave LDS in A-fragment-friendly [qrow][key] layout
#pragma unroll
    for (int c = 0; c < 4; ++c) {
#pragma unroll
      for (int r = 0; r < 4; ++r) sP[w][lg * 4 + r][c * 16 + lr] = (bf16_t)pv[c][r];
    }
    __syncthreads();

    // PV: acc += P(16x64) * V(64x192)
#pragma unroll
    for (int ks2 = 0; ks2 < 2; ++ks2) {
      bf16x8 pf = *reinterpret_cast<const bf16x8*>(&sP[w][lr][ks2 * 32 + lg * 8]);
#pragma unroll
      for (int c2 = 0; c2 < 12; ++c2) {
        bf16x8 vf = *reinterpret_cast<const bf16x8*>(&sV[c2 * 16 + lr][ks2 * 32 + lg * 8]);
        acc[c2] = __builtin_amdgcn_mfma_f32_16x16x32_bf16(pf, vf, acc[c2], 0, 0, 0);
      }
    }
    __syncthreads();
  }

  // epilogue: normalize and store (b, s, h*192 + d) bf16
#pragma unroll
  for (int c2 = 0; c2 < 12; ++c2) {
#pragma unroll
    for (int r = 0; r < 4; ++r) {
      int i = qt * QB + w * 16 + lg * 4 + r;
      size_t off = (size_t)(b * S_ + i) * QKD + h * DH_ + c2 * 16 + lr;
      attn[off] = (bf16_t)(acc[c2][r] / lden[r]);
    }
  }
}

// ---------------- launch ----------------
extern "C" void kernel_launch(void* const* d_in, const int* in_sizes, int n_in,
                              void* d_out, int out_size, void* d_ws, size_t ws_size,
                              hipStream_t stream) {
  const float* x        = (const float*)d_in[0];
  const float* w_qa     = (const float*)d_in[1];
  const float* q_norm_w = (const float*)d_in[2];
  const float* w_qb     = (const float*)d_in[3];
  const float* w_k      = (const float*)d_in[4];
  const float* w_v      = (const float*)d_in[5];
  const float* w_o      = (const float*)d_in[6];
  const float* attn_sink= (const float*)d_in[7];
  float* out = (float*)d_out;

  char* ws = (char*)d_ws;
  size_t off = 0;
  auto alloc = [&](size_t bytes) -> void* {
    void* p = ws + off;
    off += (bytes + 255) & ~(size_t)255;
    return p;
  };
  // persistent through attention / final GEMM
  bf16_t* q_b  = (bf16_t*)alloc((size_t)NROWS * QKD * 2);
  bf16_t* k_b  = (bf16_t*)alloc((size_t)NROWS * DH_ * 2);
  bf16_t* vt_b = (bf16_t*)alloc((size_t)DH_ * NROWS * 2);
  bf16_t* wo_b = (bf16_t*)alloc((size_t)QKD * HID_ * 2);
  // temps (dead before attention) — attn buffer overlays them
  size_t temp_start = off;
  bf16_t* xb    = (bf16_t*)alloc((size_t)NROWS * HID_ * 2);
  bf16_t* wqa_b = (bf16_t*)alloc((size_t)HID_ * QL_ * 2);
  bf16_t* wqb_b = (bf16_t*)alloc((size_t)QL_ * QKD * 2);
  bf16_t* wk_b  = (bf16_t*)alloc((size_t)HID_ * DH_ * 2);
  bf16_t* wv_b  = (bf16_t*)alloc((size_t)HID_ * DH_ * 2);
  bf16_t* qa_b  = (bf16_t*)alloc((size_t)NROWS * QL_ * 2);
  bf16_t* attn_b = (bf16_t*)(ws + temp_start);   // 25.2MB <= temp region 27.9MB

  auto cast = [&](const float* src, bf16_t* dst, size_t n) {
    int n4 = (int)(n / 4);
    cast_f32_to_bf16<<<dim3((n4 + 255) / 256), dim3(256), 0, stream>>>(src, dst, n4);
  };
  cast(x,    xb,    (size_t)NROWS * HID_);
  cast(w_qa, wqa_b, (size_t)HID_ * QL_);
  cast(w_qb, wqb_b, (size_t)QL_ * QKD);
  cast(w_k,  wk_b,  (size_t)HID_ * DH_);
  cast(w_v,  wv_b,  (size_t)HID_ * DH_);
  cast(w_o,  wo_b,  (size_t)QKD * HID_);

  // q_a = rmsnorm(x @ w_qa)
  gemm_kernel<1><<<dim3(QL_ / BN, NROWS / BM), 256, 0, stream>>>(xb, wqa_b, qa_b, NROWS, QL_, HID_);
  rmsnorm_kernel<<<dim3(NROWS), dim3(64), 0, stream>>>(qa_b, q_norm_w);
  // q = q_a @ w_qb
  gemm_kernel<1><<<dim3(QKD / BN, NROWS / BM), 256, 0, stream>>>(qa_b, wqb_b, q_b, NROWS, QKD, QL_);
  // k = x @ w_k ; v^T = (x @ w_v)^T
  gemm_kernel<1><<<dim3(DH_ / BN, NROWS / BM), 256, 0, stream>>>(xb, wk_b, k_b, NROWS, DH_, HID_);
  gemm_kernel<2><<<dim3(DH_ / BN, NROWS / BM), 256, 0, stream>>>(xb, wv_b, vt_b, NROWS, DH_, HID_);
  // RoPE (in place)
  rope_q_kernel<<<dim3((NROWS * H_ * 32) / 256), dim3(256), 0, stream>>>(q_b);
  rope_k_kernel<<<dim3((NROWS * 32) / 256), dim3(256), 0, stream>>>(k_b);
  // attention
  attn_kernel<<<dim3(S_ / QB, B_ * H_), dim3(256), 0, stream>>>(q_b, k_b, vt_b, attn_sink, attn_b);
  // out = attn @ w_o  (f32 out)
  gemm_kernel<0><<<dim3(HID_ / BN, NROWS / BM), 256, 0, stream>>>(attn_b, wo_b, out, NROWS, HID_, QKD);
}